// Round 5
// baseline (151.614 us; speedup 1.0000x reference)
//
#include <hip/hip_runtime.h>
#include <math.h>

#define D_DIM   1024
#define N_MODES 16
#define NPAIR   8           // modes packed 2-per-VGPR-pair for v_pk_fma_f32
#define B_DIM   8
#define L_DIM   4096
#define CHUNK   64          // per-lane time chunk: 64 lanes * 64 = L
#define SCALE_F 0.25f       // sqrt(1/N)
#define WPB     4           // waves per 256-thread block, one row per wave
#define GROUP1  16          // phase-1 elems per rolled iter (prefetched)
#define GROUP2  32          // phase-2 elems per iter: 128B stores = full TCC line

typedef float v2f __attribute__((ext_vector_type(2)));

// ---- guaranteed packed fp32 math (VOP3P). R4 evidence: VALU issue time was
// ~2.8x the packed-math estimate -> compiler likely emitted scalar FMAs.
__device__ __forceinline__ v2f pk_fma(v2f a, v2f b, v2f c) {   // a*b + c
    v2f d;
    asm("v_pk_fma_f32 %0, %1, %2, %3" : "=v"(d) : "v"(a), "v"(b), "v"(c));
    return d;
}
__device__ __forceinline__ v2f pk_fma_na(v2f a, v2f b, v2f c) { // -a*b + c
    v2f d;
    asm("v_pk_fma_f32 %0, %1, %2, %3 neg_lo:[1,0,0] neg_hi:[1,0,0]"
        : "=v"(d) : "v"(a), "v"(b), "v"(c));
    return d;
}
__device__ __forceinline__ v2f pk_mul(v2f a, v2f b) {           // a*b
    v2f d;
    asm("v_pk_mul_f32 %0, %1, %2" : "=v"(d) : "v"(a), "v"(b));
    return d;
}

// scan-phase helper (tiny op count; plain C is fine here)
__device__ __forceinline__ v2f fma2(v2f a, v2f b, v2f c) {
#if __has_builtin(__builtin_elementwise_fma)
    return __builtin_elementwise_fma(a, b, c);
#else
    v2f r; r.x = fmaf(a.x, b.x, c.x); r.y = fmaf(a.y, b.y, c.y); return r;
#endif
}

// Phase 2: recurrence from carry state + projection + residual.
// GROUP=32: 8 float4 loads -> 32 updates -> 8 float4 stores back-to-back, so
// each 128B TCC line is completed within one burst (kills the 1.83x write amp).
template<bool USE_CI, int GROUP>
__device__ __forceinline__ void phase2_run(const float* __restrict__ xrow,
                                           float* __restrict__ yrow,
                                           const v2f (&qr)[NPAIR],
                                           const v2f (&qi)[NPAIR],
                                           v2f (&hr)[NPAIR],
                                           v2f (&hi)[NPAIR],
                                           const v2f (&cr)[NPAIR],
                                           const v2f (&ci)[NPAIR],
                                           float om)
{
#pragma unroll 1
    for (int g = 0; g < CHUNK / GROUP; ++g) {
        float4 buf[GROUP / 4];
#pragma unroll
        for (int v = 0; v < GROUP / 4; ++v)
            buf[v] = *reinterpret_cast<const float4*>(xrow + g * GROUP + 4 * v);

        float* bf = reinterpret_cast<float*>(buf);
#pragma unroll
        for (int e = 0; e < GROUP; ++e) {        // e compile-time: stays in regs
            const float xe = bf[e];
            v2f x2; x2.x = xe; x2.y = xe;
            v2f acc; acc.x = 0.0f; acc.y = 0.0f;
#pragma unroll
            for (int p = 0; p < NPAIR; ++p) {
                const v2f m  = pk_mul(qi[p], hr[p]);
                const v2f t  = pk_fma(qr[p], hr[p], x2);
                const v2f nr = pk_fma_na(qi[p], hi[p], t);
                const v2f ni = pk_fma(qr[p], hi[p], m);
                hr[p] = nr; hi[p] = ni;
                acc = pk_fma(cr[p], nr, acc);
                if (USE_CI) acc = pk_fma_na(ci[p], ni, acc);
            }
            bf[e] = fmaf(om, xe, acc.x + acc.y);
        }
#pragma unroll
        for (int v = 0; v < GROUP / 4; ++v)      // full 128B line per burst
            *reinterpret_cast<float4*>(yrow + g * GROUP + 4 * v) = buf[v];
    }
}

__global__ __launch_bounds__(256)   // no min-waves clamp: (256,4) forced 64 VGPR + spills in R2
void ema_scan_kernel(const float* __restrict__ x,
                     const float* __restrict__ p_logit,
                     const float* __restrict__ lqr,
                     const float* __restrict__ lqi,
                     const float* __restrict__ gr,
                     const float* __restrict__ gi,
                     const float* __restrict__ omega,
                     float* __restrict__ out)
{
    const int wave = threadIdx.x >> 6;
    const int lane = threadIdx.x & 63;
    const int row  = blockIdx.x * WPB + wave;     // b * D + d
    const int d    = row & (D_DIM - 1);

    // ---- per-mode pole q = exp(log_q), packed 2 modes per v2f ----
    v2f qr[NPAIR], qi[NPAIR];
#pragma unroll
    for (int n = 0; n < N_MODES; ++n) {
        const int idx = d * N_MODES + n;
        const float er = __expf(lqr[idx]);
        float s, c;
        __sincosf(lqi[idx], &s, &c);
        qr[n >> 1][n & 1] = er * c;
        qi[n >> 1][n & 1] = er * s;
    }

    const float* xrow = x   + (size_t)row * L_DIM + (size_t)lane * CHUNK;
    float*       yrow = out + (size_t)row * L_DIM + (size_t)lane * CHUNK;

    v2f hr[NPAIR], hi[NPAIR];
#pragma unroll
    for (int p = 0; p < NPAIR; ++p) { hr[p] = (v2f)(0.0f); hi[p] = (v2f)(0.0f); }

    // ---- phase 1: local recurrence from zero state (rolled + prefetch) ----
    {
        float4 buf[GROUP1 / 4];
#pragma unroll
        for (int v = 0; v < GROUP1 / 4; ++v)
            buf[v] = *reinterpret_cast<const float4*>(xrow + 4 * v);

#pragma unroll 1
        for (int g = 0; g < CHUNK / GROUP1; ++g) {
            const int gn = (g < CHUNK / GROUP1 - 1) ? g + 1 : g;  // clamped prefetch
            float4 nxt[GROUP1 / 4];
#pragma unroll
            for (int v = 0; v < GROUP1 / 4; ++v)
                nxt[v] = *reinterpret_cast<const float4*>(xrow + gn * GROUP1 + 4 * v);

            const float* bf = reinterpret_cast<const float*>(buf);
#pragma unroll
            for (int e = 0; e < GROUP1; ++e) {
                v2f x2; x2.x = bf[e]; x2.y = bf[e];
#pragma unroll
                for (int p = 0; p < NPAIR; ++p) {
                    const v2f m  = pk_mul(qi[p], hr[p]);
                    const v2f t  = pk_fma(qr[p], hr[p], x2);
                    const v2f nr = pk_fma_na(qi[p], hi[p], t);
                    const v2f ni = pk_fma(qr[p], hi[p], m);
                    hr[p] = nr; hi[p] = ni;
                }
            }
#pragma unroll
            for (int v = 0; v < GROUP1 / 4; ++v) buf[v] = nxt[v];
        }
    }

    // ---- ratio A = q^CHUNK via 6 squarings (packed) ----
    v2f rr[NPAIR], ri[NPAIR];
#pragma unroll
    for (int p = 0; p < NPAIR; ++p) { rr[p] = qr[p]; ri[p] = qi[p]; }
#pragma unroll
    for (int k = 0; k < 6; ++k) {
#pragma unroll
        for (int p = 0; p < NPAIR; ++p) {
            const v2f a = rr[p], b = ri[p];
            rr[p] = fma2(a, a, -(b * b));
            ri[p] = (v2f)(2.0f) * a * b;
        }
    }

    // ---- inclusive Hillis-Steele scan across 64 lanes ----
#pragma unroll
    for (int off = 1; off < 64; off <<= 1) {
#pragma unroll
        for (int p = 0; p < NPAIR; ++p) {
            v2f pr, pi;
            pr.x = __shfl_up(hr[p].x, off); pr.y = __shfl_up(hr[p].y, off);
            pi.x = __shfl_up(hi[p].x, off); pi.y = __shfl_up(hi[p].y, off);
            if (lane >= off) {
                const v2f t0 = fma2(rr[p], pr, fma2(-ri[p], pi, hr[p]));
                const v2f t1 = fma2(rr[p], pi, fma2( ri[p], pr, hi[p]));
                hr[p] = t0; hi[p] = t1;
            }
        }
        if (off < 32) {
#pragma unroll
            for (int p = 0; p < NPAIR; ++p) {
                const v2f a = rr[p], b = ri[p];
                rr[p] = fma2(a, a, -(b * b));
                ri[p] = (v2f)(2.0f) * a * b;
            }
        }
    }

    // ---- exclusive: carry-in = inclusive value of lane-1 (0 for lane 0) ----
#pragma unroll
    for (int p = 0; p < NPAIR; ++p) {
        v2f pr, pi;
        pr.x = __shfl_up(hr[p].x, 1); pr.y = __shfl_up(hr[p].y, 1);
        pi.x = __shfl_up(hi[p].x, 1); pi.y = __shfl_up(hi[p].y, 1);
        hr[p] = (lane == 0) ? (v2f)(0.0f) : pr;
        hi[p] = (lane == 0) ? (v2f)(0.0f) : pi;
    }

    // ---- projection coefficients (loaded after scan: shorter live range) ----
    v2f cr[NPAIR], ci[NPAIR];
    bool ci_zero = true;
#pragma unroll
    for (int n = 0; n < N_MODES; ++n) {
        const int idx = d * N_MODES + n;
        const float p = 1.0f / (1.0f + __expf(-p_logit[idx]));
        const float g = SCALE_F * p;
        cr[n >> 1][n & 1] = gr[idx] * g;
        ci[n >> 1][n & 1] = gi[idx] * g;
        ci_zero = ci_zero && (gi[idx] == 0.0f);
    }
    const float om = omega[d];

    // d is wave-uniform -> branch is wave-uniform; ci==0 on the actual data.
    // USE_CI path gets GROUP=8 so its extra ci regs don't set peak pressure.
    if (ci_zero)
        phase2_run<false, GROUP2>(xrow, yrow, qr, qi, hr, hi, cr, ci, om);
    else
        phase2_run<true, 8>(xrow, yrow, qr, qi, hr, hi, cr, ci, om);
}

extern "C" void kernel_launch(void* const* d_in, const int* in_sizes, int n_in,
                              void* d_out, int out_size, void* d_ws, size_t ws_size,
                              hipStream_t stream)
{
    const float* x   = (const float*)d_in[0];
    const float* pl  = (const float*)d_in[1];
    const float* lqr = (const float*)d_in[2];
    const float* lqi = (const float*)d_in[3];
    const float* gr  = (const float*)d_in[4];
    const float* gi  = (const float*)d_in[5];
    const float* om  = (const float*)d_in[6];
    float* out = (float*)d_out;

    dim3 grid((B_DIM * D_DIM) / WPB);   // one 64-lane wave per (b, d) row
    dim3 block(64 * WPB);
    ema_scan_kernel<<<grid, block, 0, stream>>>(x, pl, lqr, lqi, gr, gi, om, out);
}

// Round 6
// 79.474 us; speedup vs baseline: 1.9077x; 1.9077x over previous
//
#include <hip/hip_runtime.h>
#include <hip/hip_bf16.h>
#include <math.h>

#define D_DIM   1024
#define NM      16
#define B_DIM   8
#define L_DIM   4096
#define SCALE_F 0.25f      // sqrt(1/N)
#define NK      5          // MFMA K-steps of 32 -> 160 taps total
#define WPB     4          // waves per block, one (b,d) row per wave
#define WIN     512        // staged x window (floats) per tile
#define NTILE   16         // 4096 / 256 output tiles per row

typedef __attribute__((ext_vector_type(8))) short bf16x8;   // 8 bf16 (4 VGPRs)
typedef __attribute__((ext_vector_type(4))) float f32x4;

union U4 { uint4 u; bf16x8 v; };

__device__ __forceinline__ unsigned rot16(unsigned v) { return (v >> 16) | (v << 16); }
__device__ __forceinline__ unsigned short f2bf(float f) {
    __hip_bfloat16 h = __float2bfloat16(f);               // RNE
    return *reinterpret_cast<unsigned short*>(&h);
}
__device__ __forceinline__ float bflo(unsigned u) { return __uint_as_float(u << 16); }
__device__ __forceinline__ float bfhi(unsigned u) { return __uint_as_float(u & 0xffff0000u); }

// A-fragments for row-dimension d: A[i,t'] = k_d[i + t'], i = lane&15,
// t' = 32*k + 8*(lane>>4) + e - 15, e = 0..7 (zero for negative tap index).
// k_d[t] = Re(sum_n c_n q_n^t) evaluated directly per t (no error accumulation).
__device__ void compute_afrag(int d, int lane,
                              const float* __restrict__ p_logit,
                              const float* __restrict__ lqr,
                              const float* __restrict__ lqi,
                              const float* __restrict__ gr,
                              const float* __restrict__ gi,
                              bf16x8 (&af)[NK])
{
    float LR[NM], LI[NM], CR[NM], CI[NM];
#pragma unroll
    for (int n = 0; n < NM; ++n) {
        const int idx = d * NM + n;
        const float p = 1.0f / (1.0f + __expf(-p_logit[idx]));
        LR[n] = lqr[idx]; LI[n] = lqi[idx];
        CR[n] = gr[idx] * (SCALE_F * p);
        CI[n] = gi[idx] * (SCALE_F * p);
    }
    const int i = lane & 15, g = lane >> 4;
#pragma unroll
    for (int k = 0; k < NK; ++k) {
        unsigned pk[4] = {0, 0, 0, 0};
#pragma unroll
        for (int e = 0; e < 8; ++e) {
            const int t = i - 15 + 32 * k + 8 * g + e;
            float v = 0.0f;
            if (t >= 0) {
                const float tf = (float)t;
#pragma unroll
                for (int n = 0; n < NM; ++n) {
                    const float er = __expf(tf * LR[n]);
                    float s, c; __sincosf(tf * LI[n], &s, &c);
                    v += er * fmaf(CR[n], c, -CI[n] * s);
                }
            }
            const unsigned b = f2bf(v);
            if ((e & 1) == 0) pk[e >> 1] = b; else pk[e >> 1] |= b << 16;
        }
        U4 u; u.u = make_uint4(pk[0], pk[1], pk[2], pk[3]); af[k] = u.v;
    }
}

// Kernel A: precompute A-fragments for all d into ws, in the exact per-lane
// order the main kernel loads (fully coalesced dwordx4 both sides).
__global__ __launch_bounds__(64)
void ema_mkA(const float* __restrict__ p_logit, const float* __restrict__ lqr,
             const float* __restrict__ lqi, const float* __restrict__ gr,
             const float* __restrict__ gi, uint4* __restrict__ wsa)
{
    const int d = blockIdx.x, lane = threadIdx.x;
    bf16x8 af[NK];
    compute_afrag(d, lane, p_logit, lqr, lqi, gr, gi, af);
#pragma unroll
    for (int k = 0; k < NK; ++k) {
        U4 u; u.v = af[k];
        wsa[(size_t)(d * NK + k) * 64 + lane] = u.u;
    }
}

// Main kernel: one wave per (b,d) row; 16 tiles of 256 outputs.
// Per tile: stage x[l0-256 .. l0+255] into wave-private LDS as bf16 (no
// barriers needed), then 5x { ds_read_b128 + half-word-reverse + MFMA },
// fused omega*x residual, dwordx4 stores (full 128B lines across the wave).
template<bool FROM_WS>
__global__ __launch_bounds__(256)
void ema_fir(const float* __restrict__ x,
             const float* __restrict__ p_logit,
             const float* __restrict__ lqr, const float* __restrict__ lqi,
             const float* __restrict__ gr, const float* __restrict__ gi,
             const float* __restrict__ omega,
             const uint4* __restrict__ wsa,
             float* __restrict__ out)
{
    __shared__ __align__(16) unsigned short smem[WPB][WIN];

    const int w    = threadIdx.x >> 6;
    const int lane = threadIdx.x & 63;
    const int row  = blockIdx.x * WPB + w;      // b*D + d
    const int d    = row & (D_DIM - 1);
    const int j    = lane & 15, g = lane >> 4;

    const float* xrow = x   + (size_t)row * L_DIM;
    float*       yrow = out + (size_t)row * L_DIM;
    const float  om   = omega[d];

    bf16x8 af[NK];
    if (FROM_WS) {
#pragma unroll
        for (int k = 0; k < NK; ++k) {
            U4 u; u.u = wsa[(size_t)(d * NK + k) * 64 + lane];
            af[k] = u.v;
        }
    } else {
        compute_afrag(d, lane, p_logit, lqr, lqi, gr, gi, af);
    }

    char* sbase = reinterpret_cast<char*>(&smem[w][0]);

#pragma unroll 1
    for (int t = 0; t < NTILE; ++t) {
        const int l0 = t * 256;

        // ---- stage 512-float window [l0-256, l0+255] as bf16 into LDS ----
        const int idx0 = l0 - 256 + lane * 8;
        float f[8];
        if (idx0 >= 0) {                         // whole-lane OOB only (tile 0)
            const float4 a = *reinterpret_cast<const float4*>(xrow + idx0);
            const float4 b = *reinterpret_cast<const float4*>(xrow + idx0 + 4);
            f[0] = a.x; f[1] = a.y; f[2] = a.z; f[3] = a.w;
            f[4] = b.x; f[5] = b.y; f[6] = b.z; f[7] = b.w;
        } else {
#pragma unroll
            for (int u = 0; u < 8; ++u) f[u] = 0.0f;
        }
        uint4 pk;
        pk.x = f2bf(f[0]) | ((unsigned)f2bf(f[1]) << 16);
        pk.y = f2bf(f[2]) | ((unsigned)f2bf(f[3]) << 16);
        pk.z = f2bf(f[4]) | ((unsigned)f2bf(f[5]) << 16);
        pk.w = f2bf(f[6]) | ((unsigned)f2bf(f[7]) << 16);
        *reinterpret_cast<uint4*>(sbase + lane * 16) = pk;
        // same-wave ds_write -> ds_read: compiler inserts lgkmcnt; no barrier.

        // ---- 5 K-steps: B[t',j] = x[l0+16j-t'] (8 contiguous bf16, reversed) ----
        f32x4 acc = {0.0f, 0.0f, 0.0f, 0.0f};
#pragma unroll
        for (int k = 0; k < NK; ++k) {
            const int boff = 528 + 32 * j - 64 * k - 16 * g;   // bytes, 16B aligned
            U4 z; z.u = *reinterpret_cast<const uint4*>(sbase + boff);
            uint4 rv;
            rv.x = rot16(z.u.w); rv.y = rot16(z.u.z);
            rv.z = rot16(z.u.y); rv.w = rot16(z.u.x);
            U4 bf; bf.u = rv;
            acc = __builtin_amdgcn_mfma_f32_16x16x32_bf16(af[k], bf.v, acc, 0, 0, 0);
        }

        // ---- epilogue: += omega*x, store 4 consecutive outputs per lane ----
        const int lx = 512 + 32 * j + 8 * g;     // byte offset of x at output pos
        const uint2 z2 = *reinterpret_cast<const uint2*>(sbase + lx);
        f32x4 o;
        o.x = fmaf(om, bflo(z2.x), acc.x);
        o.y = fmaf(om, bfhi(z2.x), acc.y);
        o.z = fmaf(om, bflo(z2.y), acc.z);
        o.w = fmaf(om, bfhi(z2.y), acc.w);
        *reinterpret_cast<f32x4*>(yrow + l0 + 16 * j + 4 * g) = o;
    }
}

extern "C" void kernel_launch(void* const* d_in, const int* in_sizes, int n_in,
                              void* d_out, int out_size, void* d_ws, size_t ws_size,
                              hipStream_t stream)
{
    const float* x   = (const float*)d_in[0];
    const float* pl  = (const float*)d_in[1];
    const float* lqr = (const float*)d_in[2];
    const float* lqi = (const float*)d_in[3];
    const float* gr  = (const float*)d_in[4];
    const float* gi  = (const float*)d_in[5];
    const float* om  = (const float*)d_in[6];
    float* out = (float*)d_out;

    const size_t needA = (size_t)D_DIM * NK * 64 * 16;   // 5.24 MB of A-fragments
    dim3 grid((B_DIM * D_DIM) / WPB), block(64 * WPB);

    if (ws_size >= needA) {
        ema_mkA<<<dim3(D_DIM), dim3(64), 0, stream>>>(pl, lqr, lqi, gr, gi,
                                                      (uint4*)d_ws);
        ema_fir<true><<<grid, block, 0, stream>>>(x, pl, lqr, lqi, gr, gi, om,
                                                  (const uint4*)d_ws, out);
    } else {
        ema_fir<false><<<grid, block, 0, stream>>>(x, pl, lqr, lqi, gr, gi, om,
                                                   nullptr, out);
    }
}